// Round 3
// baseline (3186.579 us; speedup 1.0000x reference)
//
#include <hip/hip_runtime.h>

#define T_ 512
#define B_ 256
#define D_ 256
#define H_ 256

typedef short s16x8 __attribute__((ext_vector_type(8)));
typedef float f32x4 __attribute__((ext_vector_type(4)));

static __device__ __forceinline__ unsigned short f2bf(float f){
  unsigned u = __float_as_uint(f);
  u += 0x7FFFu + ((u >> 16) & 1u);
  return (unsigned short)(u >> 16);
}
static __device__ __forceinline__ float bf2f(unsigned short h){
  return __uint_as_float(((unsigned)h) << 16);
}
static __device__ __forceinline__ unsigned pk2(float a, float b){
  return (unsigned)f2bf(a) | ((unsigned)f2bf(b) << 16);
}
static __device__ __forceinline__ float sigf(float x){
  return __builtin_amdgcn_rcpf(1.0f + __expf(-x));
}
static __device__ __forceinline__ float tanhf_(float x){
  return 1.0f - 2.0f * __builtin_amdgcn_rcpf(__expf(2.0f * x) + 1.0f);
}

// ---------------- kernel 0a: split W into Wx / Wh bf16 copies ----------------
__global__ void k_cast(const float* __restrict__ W,
                       unsigned short* __restrict__ Wxb,
                       unsigned short* __restrict__ Whb)
{
  const int i = blockIdx.x * 256 + threadIdx.x;   // 0 .. 1024*256-1
  const int row = i >> 8;
  const int k = i & 255;
  Wxb[i] = f2bf(W[(size_t)row * 512 + k]);
  Whb[i] = f2bf(W[(size_t)row * 512 + 256 + k]);
}

// ---------------- kernel 0b: cast x (T*B*D f32) -> bf16 ----------------
__global__ void k_cast_x(const float* __restrict__ x,
                         unsigned short* __restrict__ xb)
{
  const size_t i = ((size_t)blockIdx.x * 256 + threadIdx.x) * 8;
  const float4 a = *(const float4*)(x + i);
  const float4 b = *(const float4*)(x + i + 4);
  uint4 w;
  w.x = pk2(a.x, a.y);  w.y = pk2(a.z, a.w);
  w.z = pk2(b.x, b.y);  w.w = pk2(b.z, b.w);
  *(uint4*)(xb + i) = w;
}

// ---------------- phase 1: zx = Wx * x^T + b, stored in MFMA C-fragment layout
// M = 1024 rows (g,q), N = (t,b) flat, K = 256.  A-tile resident, 16 n-tiles/WG.
// zx layout: [n16tile(chunk-local)][m16tile 0..63][lane 0..63][4 bf16]  (512B per tile)
__global__ __launch_bounds__(512, 2) void k_phase1(
    const unsigned short* __restrict__ Wxb,
    const unsigned short* __restrict__ xb,
    const float* __restrict__ bias,
    unsigned short* __restrict__ zxf,
    int t0)
{
  extern __shared__ char smem[];          // [0,64K): A = Wx tile, [64K,128K): B = x tile (bf16, swizzled)
  char* Bs = smem + 65536;
  const int tid  = threadIdx.x;
  const int lane = tid & 63;
  const int wid  = tid >> 6;
  const int r16  = lane >> 4;
  const int c16  = lane & 15;
  const int wm = wid >> 2;   // 0..1
  const int wn = wid & 3;    // 0..3
  const int mbase  = blockIdx.y * 128;
  const int ntile0 = blockIdx.x * 16;
  const size_t nbase = (size_t)t0 * 256 + (size_t)ntile0 * 128;

  // stage A once: 128 rows of Wxb (64KB), swizzled
#pragma unroll
  for (int r = 0; r < 8; ++r){
    const int ch = r * 512 + tid;
    const int row = ch >> 5;
    const int cc = ch & 31;
    uint4 v = *(const uint4*)(Wxb + (size_t)(mbase + row) * 256 + cc * 8);
    *(uint4*)(smem + row * 512 + ((cc * 16) ^ ((row & 7) << 4))) = v;
  }
  // bias in regs
  float bv[4][4];
#pragma unroll
  for (int mt = 0; mt < 4; ++mt)
#pragma unroll
    for (int i = 0; i < 4; ++i)
      bv[mt][i] = bias[mbase + wm * 64 + mt * 16 + r16 * 4 + i];

  // prefetch B tile 0 into regs
  uint4 pb[8];
#pragma unroll
  for (int r = 0; r < 8; ++r){
    const int ch = r * 512 + tid;
    const int row = ch >> 5;
    const int cc = ch & 31;
    pb[r] = *(const uint4*)(xb + (nbase + row) * 256 + cc * 8);
  }

  for (int it = 0; it < 16; ++it){
    __syncthreads();   // previous iteration's reads done (it=0: nothing; also orders A writes)
#pragma unroll
    for (int r = 0; r < 8; ++r){
      const int ch = r * 512 + tid;
      const int row = ch >> 5;
      const int cc = ch & 31;
      *(uint4*)(Bs + row * 512 + ((cc * 16) ^ ((row & 7) << 4))) = pb[r];
    }
    __syncthreads();   // B visible
    if (it < 15){
      const size_t nb = nbase + (size_t)(it + 1) * 128;
#pragma unroll
      for (int r = 0; r < 8; ++r){
        const int ch = r * 512 + tid;
        const int row = ch >> 5;
        const int cc = ch & 31;
        pb[r] = *(const uint4*)(xb + (nb + row) * 256 + cc * 8);
      }
    }

    f32x4 acc[4][2];
#pragma unroll
    for (int mt = 0; mt < 4; ++mt)
#pragma unroll
      for (int i = 0; i < 4; ++i){
        acc[mt][0][i] = bv[mt][i];
        acc[mt][1][i] = bv[mt][i];
      }

#pragma unroll
    for (int kc = 0; kc < 8; ++kc){
      s16x8 bf[2];
#pragma unroll
      for (int nt = 0; nt < 2; ++nt){
        const int row = wn * 32 + nt * 16 + c16;
        bf[nt] = *(const s16x8*)(Bs + row * 512 + ((kc * 64 + r16 * 16) ^ ((row & 7) << 4)));
      }
#pragma unroll
      for (int mt = 0; mt < 4; ++mt){
        const int row = wm * 64 + mt * 16 + c16;
        const s16x8 af = *(const s16x8*)(smem + row * 512 + ((kc * 64 + r16 * 16) ^ ((row & 7) << 4)));
#pragma unroll
        for (int nt = 0; nt < 2; ++nt)
          acc[mt][nt] = __builtin_amdgcn_mfma_f32_16x16x32_bf16(af, bf[nt], acc[mt][nt], 0, 0, 0);
      }
    }

    const int ntile = ntile0 + it;
#pragma unroll
    for (int mt = 0; mt < 4; ++mt)
#pragma unroll
      for (int ss = 0; ss < 2; ++ss){
        const int m16 = (mbase >> 4) + wm * 4 + mt;
        const size_t n16 = (size_t)ntile * 8 + wn * 2 + ss;   // chunk-local (t,b)/16
        uint2 p;
        p.x = pk2(acc[mt][ss][0], acc[mt][ss][1]);
        p.y = pk2(acc[mt][ss][2], acc[mt][ss][3]);
        *(uint2*)((char*)zxf + (n16 * 64 + m16) * 512 + lane * 8) = p;
      }
  }
}

// ---------------- phase 2: the recurrence, q-split across 32 WGs.
// WG (bt = blockIdx.x>>1, half = blockIdx.x&1) computes h[bt*16..+16][half*128..+128].
// All 4 gates' Wh rows for this q-half live in registers (wf[4][8] = 128 VGPR).
// LDS: 2 x 8KB h double-buffer only. Pairwise h exchange via hx[] + seq flags in L3.
__global__ __launch_bounds__(512, 2) void k_phase2(
    const unsigned short* __restrict__ Whb,
    const unsigned short* __restrict__ zxf,
    float* __restrict__ out,
    unsigned short* __restrict__ sh,
    float* __restrict__ sc,
    unsigned short* __restrict__ hx,   // [2 parity][16 bt][2 half][32 qg][16 b] x uint2
    int* __restrict__ flags,           // [16 bt][2 half], 64B padded
    int t0, int TC)
{
  extern __shared__ char smem[];       // hbuf parity 0: [0,8K), parity 1: [8K,16K)
  const int tid  = threadIdx.x;
  const int lane = tid & 63;
  const int wid  = tid >> 6;
  const int r16  = lane >> 4;
  const int c16  = lane & 15;
  const int bt   = blockIdx.x >> 1;
  const int half = blockIdx.x & 1;
  const int b    = bt * 16 + c16;
  const int q    = half * 128 + wid * 16 + r16 * 4;   // this lane's 4 output rows

  // Wh A-fragments: all 4 gates, m16 tile = g*16 + half*8 + wid, kc 0..7
  s16x8 wf[4][8];
#pragma unroll
  for (int g = 0; g < 4; ++g){
    const int row = (g * 16 + half * 8 + wid) * 16 + c16;
    const unsigned short* wp = Whb + (size_t)row * 256 + r16 * 8;
#pragma unroll
    for (int kc = 0; kc < 8; ++kc)
      wf[g][kc] = *(const s16x8*)(wp + kc * 32);
  }

  float cst[4];
  if (t0 == 0){
#pragma unroll
    for (int i = 0; i < 4; ++i) cst[i] = 0.0f;
    *(uint4*)(smem + tid * 16) = make_uint4(0, 0, 0, 0);   // zero hbuf[0] (8KB)
  } else {
    const float4 cv = *(const float4*)(sc + (size_t)b * 256 + q);
    cst[0] = cv.x; cst[1] = cv.y; cst[2] = cv.z; cst[3] = cv.w;
    // stage full h_t0 (256 q x 16 b = 8KB) from sh into hbuf[t0&1]
    const int b2 = tid & 15;
    const int qq = (tid >> 4) * 8;
    uint4 v = *(const uint4*)(sh + (size_t)(bt * 16 + b2) * 256 + qq);
    *(uint4*)(smem + ((t0 & 1) << 13) + b2 * 512 + ((qq * 2) ^ ((b2 & 7) << 4))) = v;
  }
  __syncthreads();

  const char* zlane = (const char*)zxf + (size_t)lane * 8;
  const int mt0 = half * 8 + wid;      // my m16 tile column within each gate
  uint2 zc[4], zn[4];
#pragma unroll
  for (int g = 0; g < 4; ++g)
    zc[g] = *(const uint2*)(zlane + ((size_t)bt * 64 + g * 16 + mt0) * 512);

  uint2 hkeep;
  const int qg = wid * 4 + r16;        // 0..31, my 4-q group within the half

  for (int t = t0; t < t0 + TC; ++t){
    const int tt = t - t0;
    const char* hread = smem + ((t & 1) << 13);
    char*      hwrite = smem + (((t & 1) ^ 1) << 13);
    const int ttn = (tt + 1 < TC) ? (tt + 1) : tt;

    // prefetch next step's zx (consumed next iteration; drained by vmcnt(0) below)
#pragma unroll
    for (int g = 0; g < 4; ++g)
      zn[g] = *(const uint2*)(zlane + (((size_t)ttn * 16 + bt) * 64 + g * 16 + mt0) * 512);

    f32x4 acc[4];
#pragma unroll
    for (int g = 0; g < 4; ++g){
      acc[g][0] = bf2f((unsigned short)(zc[g].x & 0xFFFFu));
      acc[g][1] = bf2f((unsigned short)(zc[g].x >> 16));
      acc[g][2] = bf2f((unsigned short)(zc[g].y & 0xFFFFu));
      acc[g][3] = bf2f((unsigned short)(zc[g].y >> 16));
    }

#pragma unroll
    for (int kc = 0; kc < 8; ++kc){
      const s16x8 hv = *(const s16x8*)(hread + c16 * 512 + ((kc * 64 + r16 * 16) ^ ((c16 & 7) << 4)));
      acc[0] = __builtin_amdgcn_mfma_f32_16x16x32_bf16(wf[0][kc], hv, acc[0], 0, 0, 0);
      acc[1] = __builtin_amdgcn_mfma_f32_16x16x32_bf16(wf[1][kc], hv, acc[1], 0, 0, 0);
      acc[2] = __builtin_amdgcn_mfma_f32_16x16x32_bf16(wf[2][kc], hv, acc[2], 0, 0, 0);
      acc[3] = __builtin_amdgcn_mfma_f32_16x16x32_bf16(wf[3][kc], hv, acc[3], 0, 0, 0);
    }

    float ho[4];
#pragma unroll
    for (int i = 0; i < 4; ++i){
      const float fg = sigf(__cosf(acc[0][i]));
      const float ig = sigf(__cosf(acc[1][i]));
      const float gg = tanhf_(__cosf(acc[2][i]));
      const float og = sigf(__cosf(acc[3][i]));
      const float cn = fg * cst[i] + ig * gg;
      cst[i] = cn;
      ho[i] = og * tanhf_(cn);
    }
    *(float4*)(out + ((size_t)t * B_ + b) * H_ + q) = make_float4(ho[0], ho[1], ho[2], ho[3]);
    hkeep = make_uint2(pk2(ho[0], ho[1]), pk2(ho[2], ho[3]));
    // own h -> next parity LDS buffer
    *(uint2*)(hwrite + c16 * 512 + ((q * 2) ^ ((c16 & 7) << 4))) = hkeep;
    if (t == T_ - 1){
      float* hl = out + (size_t)T_ * B_ * H_;
      *(float4*)(hl + (size_t)b * H_ + q) = make_float4(ho[0], ho[1], ho[2], ho[3]);
      float* cl = hl + (size_t)B_ * H_;
      *(float4*)(cl + (size_t)b * H_ + q) = make_float4(cst[0], cst[1], cst[2], cst[3]);
    } else {
      // publish own h-half to the exchange buffer (parity (t+1)&1)
      const size_t slot = ((((size_t)((t + 1) & 1) * 16 + bt) * 2 + half) * 32 + qg) * 16 + c16;
      *(uint2*)(hx + slot * 4) = hkeep;
    }

    asm volatile("s_waitcnt vmcnt(0)" ::: "memory");  // h-publish (and out) stores retired
    __builtin_amdgcn_s_barrier();                     // all waves' stores done

    if (t < T_ - 1){
      if (tid == 0)
        __hip_atomic_store(&flags[(bt * 2 + half) * 16], t + 1,
                           __ATOMIC_RELEASE, __HIP_MEMORY_SCOPE_AGENT);
      const int* pf = &flags[(bt * 2 + (half ^ 1)) * 16];
      while (__hip_atomic_load(pf, __ATOMIC_ACQUIRE, __HIP_MEMORY_SCOPE_AGENT) < t + 1) { }
      // stage partner's 4KB half into hwrite: thread -> (qg2, b2)
      const int b2 = tid & 15;
      const int qg2 = tid >> 4;
      const size_t pslot = ((((size_t)((t + 1) & 1) * 16 + bt) * 2 + (half ^ 1)) * 32 + qg2) * 16 + b2;
      const uint2 pv = *(const uint2*)(hx + pslot * 4);
      const int qp = (half ^ 1) * 128 + qg2 * 4;
      *(uint2*)(hwrite + b2 * 512 + ((qp * 2) ^ ((b2 & 7) << 4))) = pv;
    }
    asm volatile("s_waitcnt lgkmcnt(0)" ::: "memory");  // LDS h writes visible
    __builtin_amdgcn_s_barrier();                       // hbuf[(t+1)&1] complete

#pragma unroll
    for (int g = 0; g < 4; ++g) zc[g] = zn[g];
  }

  if (t0 + TC < T_){
    *(uint2*)(sh + (size_t)b * 256 + q) = hkeep;
    *(float4*)(sc + (size_t)b * 256 + q) = make_float4(cst[0], cst[1], cst[2], cst[3]);
  }
}

extern "C" void kernel_launch(void* const* d_in, const int* in_sizes, int n_in,
                              void* d_out, int out_size, void* d_ws, size_t ws_size,
                              hipStream_t stream)
{
  const float* x    = (const float*)d_in[0];   // [T,B,D] f32
  const float* W    = (const float*)d_in[1];   // [4,H,D+H] f32
  const float* bias = (const float*)d_in[2];   // [4,H] f32
  float* out = (float*)d_out;                  // outputs | h_last | c_last (f32)

  char* ws = (char*)d_ws;
  unsigned short* Wxb  = (unsigned short*)(ws);                    // 512 KB
  unsigned short* Whb  = (unsigned short*)(ws + 524288);           // 512 KB
  unsigned short* sh   = (unsigned short*)(ws + 1048576);          // 128 KB h state
  float*          sc   = (float*)(ws + 1179648);                   // 256 KB c state
  int*            flags= (int*)(ws + 1441792);                     // 4 KB (64B-padded flags)
  unsigned short* hx   = (unsigned short*)(ws + 1445888);          // 256 KB exchange buf
  unsigned short* xb   = (unsigned short*)(ws + 1708032);          // 64 MB x bf16
  const unsigned long long zx_off = 1708032ull + (unsigned long long)T_ * B_ * D_ * 2ull;
  unsigned short* zxf  = (unsigned short*)(ws + zx_off);           // zx fragment buffer

  (void)hipFuncSetAttribute((const void*)k_phase1, hipFuncAttributeMaxDynamicSharedMemorySize, 131072);
  (void)hipFuncSetAttribute((const void*)k_phase2, hipFuncAttributeMaxDynamicSharedMemorySize, 16384);

  int TC = 8;
  const int cands[6] = {512, 256, 128, 64, 32, 16};
  for (int i = 0; i < 6; ++i){
    if (zx_off + (unsigned long long)cands[i] * 524288ull <= (unsigned long long)ws_size){
      TC = cands[i];
      break;
    }
  }

  (void)hipMemsetAsync(flags, 0, 4096, stream);   // seq flags must start at 0 every launch
  k_cast<<<1024, 256, 0, stream>>>(W, Wxb, Whb);
  k_cast_x<<<(T_ * B_ * D_) / 2048, 256, 0, stream>>>(x, xb);
  for (int t0 = 0; t0 < T_; t0 += TC){
    k_phase1<<<dim3(TC / 8, 8, 1), 512, 131072, stream>>>(Wxb, xb, bias, zxf, t0);
    k_phase2<<<dim3(32, 1, 1), 512, 16384, stream>>>(Whb, zxf, out, sh, sc, hx, flags, t0, TC);
  }
}

// Round 7
// 2581.319 us; speedup vs baseline: 1.2345x; 1.2345x over previous
//
#include <hip/hip_runtime.h>

#define T_ 512
#define B_ 256
#define D_ 256
#define H_ 256

typedef short s16x8 __attribute__((ext_vector_type(8)));
typedef float f32x4 __attribute__((ext_vector_type(4)));
typedef unsigned short u16;

static __device__ __forceinline__ u16 f2bf(float f){
  unsigned u = __float_as_uint(f);
  u += 0x7FFFu + ((u >> 16) & 1u);
  return (u16)(u >> 16);
}
static __device__ __forceinline__ unsigned pk2(float a, float b){
  return (unsigned)f2bf(a) | ((unsigned)f2bf(b) << 16);
}
static __device__ __forceinline__ float bflo(unsigned u){
  return __uint_as_float(u << 16);
}
static __device__ __forceinline__ float bfhi(unsigned u){
  return __uint_as_float(u & 0xFFFF0000u);
}
static __device__ __forceinline__ float sigf(float x){
  return __builtin_amdgcn_rcpf(1.0f + __expf(-x));
}
static __device__ __forceinline__ float tanhf_(float x){
  return 1.0f - 2.0f * __builtin_amdgcn_rcpf(__expf(2.0f * x) + 1.0f);
}

// Fragment-granule layout: matrix stored as [tile16][kc 0..7][r16 0..3][c16 0..15]
// granules of 16B (8 bf16).  Granule (t,kc,r,c) holds M[t*16 + c][kc*32 + r*8 + j].

// ---------- kernel 0a: W -> frag-layout Wxb / Whb (bf16) ----------
__global__ void k_cast(const float* __restrict__ W,
                       u16* __restrict__ Wxb, u16* __restrict__ Whb)
{
  const int i   = blockIdx.x * 256 + threadIdx.x;   // 0..65535
  const int m   = i >> 15;                          // 0=Wx, 1=Wh
  const int idx = i & 32767;                        // granule index
  const int c16 = idx & 15;
  const int r16 = (idx >> 4) & 3;
  const int kc  = (idx >> 6) & 7;
  const int t16 = idx >> 9;
  const int row = t16 * 16 + c16;
  const int k   = kc * 32 + r16 * 8;
  const float* src = W + (size_t)row * 512 + (m ? 256 + k : k);
  const float4 a = *(const float4*)src;
  const float4 b = *(const float4*)(src + 4);
  uint4 w;
  w.x = pk2(a.x, a.y);  w.y = pk2(a.z, a.w);
  w.z = pk2(b.x, b.y);  w.w = pk2(b.z, b.w);
  u16* dst = m ? Whb : Wxb;
  *(uint4*)(dst + (size_t)idx * 8) = w;
}

// ---------- kernel 0b: x (f32 [T*B][256]) -> frag-layout xb (bf16) ----------
__global__ void k_cast_x(const float* __restrict__ x, u16* __restrict__ xb)
{
  const size_t i = (size_t)blockIdx.x * 256 + threadIdx.x;  // granule id
  const int c16 = (int)(i & 15);
  const int r16 = (int)(i >> 4) & 3;
  const int kc  = (int)(i >> 6) & 7;
  const size_t n16 = i >> 9;
  const float* src = x + (n16 * 16 + c16) * 256 + kc * 32 + r16 * 8;
  const float4 a = *(const float4*)src;
  const float4 b = *(const float4*)(src + 4);
  uint4 w;
  w.x = pk2(a.x, a.y);  w.y = pk2(a.z, a.w);
  w.z = pk2(b.x, b.y);  w.w = pk2(b.z, b.w);
  *(uint4*)(xb + i * 8) = w;
}

// ---------- phase 1: zx = Wx * x^T + b, output in C-fragment layout ----------
__global__ __launch_bounds__(512, 2) void k_phase1(
    const u16* __restrict__ Wxb, const u16* __restrict__ xb,
    const float* __restrict__ bias, u16* __restrict__ zxf, int t0)
{
  extern __shared__ char smem[];          // [0,64K) A frags, [64K,128K) B frags
  char* Bs = smem + 65536;
  const int tid  = threadIdx.x;
  const int lane = tid & 63;
  const int wid  = tid >> 6;
  const int r16  = lane >> 4;
  const int wm   = wid >> 2;              // 0..1 -> 4 m16 tiles each
  const int wn   = wid & 3;               // 0..3 -> 2 n16 tiles each
  const char* WxC = (const char*)Wxb;
  const char* xbC = (const char*)xb;
  char* zxC = (char*)zxf;

  const size_t abase = (size_t)blockIdx.y << 16;                             // 64KB per m-block
  const size_t nbase = ((size_t)t0 * 16 + (size_t)blockIdx.x * 128) << 13;   // 8KB per n16

  // stage A (linear 64KB copy)
#pragma unroll
  for (int r = 0; r < 8; ++r){
    const int o = (r * 512 + tid) * 16;
    *(uint4*)(smem + o) = *(const uint4*)(WxC + abase + o);
  }
  // bias
  float bv[4][4];
#pragma unroll
  for (int mt = 0; mt < 4; ++mt)
#pragma unroll
    for (int i = 0; i < 4; ++i)
      bv[mt][i] = bias[blockIdx.y * 128 + wm * 64 + mt * 16 + r16 * 4 + i];

  // prefetch B block 0
  uint4 pb[8];
#pragma unroll
  for (int r = 0; r < 8; ++r)
    pb[r] = *(const uint4*)(xbC + nbase + (r * 512 + tid) * 16);

  __syncthreads();   // A visible

  for (int it = 0; it < 16; ++it){
    if (it) __syncthreads();             // previous iteration's B reads done
#pragma unroll
    for (int r = 0; r < 8; ++r)
      *(uint4*)(Bs + (r * 512 + tid) * 16) = pb[r];
    __syncthreads();                     // B visible

    if (it < 15){
      const size_t nb = nbase + (size_t)(it + 1) * 65536;
#pragma unroll
      for (int r = 0; r < 8; ++r)
        pb[r] = *(const uint4*)(xbC + nb + (r * 512 + tid) * 16);
    }

    f32x4 acc[4][2];
#pragma unroll
    for (int mt = 0; mt < 4; ++mt)
#pragma unroll
      for (int i = 0; i < 4; ++i){
        acc[mt][0][i] = bv[mt][i];
        acc[mt][1][i] = bv[mt][i];
      }

#pragma unroll
    for (int kc = 0; kc < 8; ++kc){
      const s16x8 bf0 = *(const s16x8*)(Bs + ((wn * 2 + 0) << 13) + (kc << 10) + lane * 16);
      const s16x8 bf1 = *(const s16x8*)(Bs + ((wn * 2 + 1) << 13) + (kc << 10) + lane * 16);
#pragma unroll
      for (int mt = 0; mt < 4; ++mt){
        const s16x8 af = *(const s16x8*)(smem + ((wm * 4 + mt) << 13) + (kc << 10) + lane * 16);
        acc[mt][0] = __builtin_amdgcn_mfma_f32_16x16x32_bf16(af, bf0, acc[mt][0], 0, 0, 0);
        acc[mt][1] = __builtin_amdgcn_mfma_f32_16x16x32_bf16(af, bf1, acc[mt][1], 0, 0, 0);
      }
    }

#pragma unroll
    for (int mt = 0; mt < 4; ++mt)
#pragma unroll
      for (int nt = 0; nt < 2; ++nt){
        const size_t n16l = (size_t)blockIdx.x * 128 + it * 8 + wn * 2 + nt;
        const int   m16g  = blockIdx.y * 8 + wm * 4 + mt;
        uint2 p;
        p.x = pk2(acc[mt][nt][0], acc[mt][nt][1]);
        p.y = pk2(acc[mt][nt][2], acc[mt][nt][3]);
        *(uint2*)(zxC + (n16l * 64 + m16g) * 512 + lane * 8) = p;
      }
  }
}

// ---------- phase 2: R2's replay-proven structure; weight path in frag layout ----------
// Wh gates 0..2 in register A-frags, gate 3 in LDS frag tiles (128KB, linear).
// h double-buffer 2x8KB, R2's XOR-swizzled layout.  One __syncthreads per step.
__global__ __launch_bounds__(512, 2) void k_phase2(
    const u16* __restrict__ Whb, const u16* __restrict__ zxf,
    float* __restrict__ out, u16* __restrict__ sh, float* __restrict__ sc,
    int t0, int TC)
{
  extern __shared__ char smem[];   // [0,128K) gate-3 frags; [128K,136K) h0; [136K,144K) h1
  const int tid  = threadIdx.x;
  const int lane = tid & 63;
  const int wid  = tid >> 6;
  const int r16  = lane >> 4;
  const int c16  = lane & 15;
  const int bt   = blockIdx.x;
  const int b    = bt * 16 + c16;
  const char* WhC = (const char*)Whb;

  // register A-frags: gates 0..2, tiles wid*2+s  (frag-granule addressing)
  s16x8 wf[6][8];
#pragma unroll
  for (int g = 0; g < 3; ++g)
#pragma unroll
    for (int s = 0; s < 2; ++s)
#pragma unroll
      for (int kc = 0; kc < 8; ++kc)
        wf[g * 2 + s][kc] =
            *(const s16x8*)(WhC + ((g * 16 + wid * 2 + s) << 13) + (kc << 10) + lane * 16);

  // gate-3 frag tiles -> LDS (linear 128KB copy)
#pragma unroll
  for (int r = 0; r < 16; ++r){
    const int o = (r * 512 + tid) * 16;
    *(uint4*)(smem + o) = *(const uint4*)(WhC + (48 << 13) + o);
  }

  float cst[2][4];
  char* hb0 = smem + 131072;           // parity-0 h buffer (R2 layout)
  if (t0 == 0){
#pragma unroll
    for (int s = 0; s < 2; ++s)
#pragma unroll
      for (int i = 0; i < 4; ++i) cst[s][i] = 0.0f;
    *(uint4*)(hb0 + tid * 16) = make_uint4(0, 0, 0, 0);
  } else {
#pragma unroll
    for (int s = 0; s < 2; ++s){
      const int q0 = (wid * 2 + s) * 16 + r16 * 4;
      const float4 cv = *(const float4*)(sc + (size_t)b * 256 + q0);
      cst[s][0] = cv.x; cst[s][1] = cv.y; cst[s][2] = cv.z; cst[s][3] = cv.w;
    }
    const int brow = tid >> 5;
    const int cc = tid & 31;
    uint4 v = *(const uint4*)((const char*)sh + (size_t)(bt * 16 + brow) * 512 + cc * 16);
    *(uint4*)(hb0 + brow * 512 + ((cc * 16) ^ ((brow & 7) << 4))) = v;
  }
  __syncthreads();

  const char* zlane = (const char*)zxf + (size_t)lane * 8;
  // preload zc for tt = 0
  uint2 zc[2][4];
#pragma unroll
  for (int s = 0; s < 2; ++s)
#pragma unroll
    for (int g = 0; g < 4; ++g)
      zc[s][g] = *(const uint2*)(zlane + ((size_t)bt * 64 + g * 16 + wid * 2 + s) * 512);

  unsigned hpack[2][2];

  for (int t = t0; t < t0 + TC; ++t){
    const int tt = t - t0;
    const char* hread = smem + 131072 + ((tt & 1) << 13);
    char*      hwrite = smem + 131072 + (((tt & 1) ^ 1) << 13);
    const int ttn = (tt + 1 < TC) ? (tt + 1) : tt;
    const size_t znoff = ((size_t)ttn * 16 + bt) * 64 * 512;
    uint2 zn[2][4];

#pragma unroll
    for (int s = 0; s < 2; ++s){
      f32x4 acc[4];
#pragma unroll
      for (int g = 0; g < 4; ++g){
        acc[g][0] = bflo(zc[s][g].x);
        acc[g][1] = bfhi(zc[s][g].x);
        acc[g][2] = bflo(zc[s][g].y);
        acc[g][3] = bfhi(zc[s][g].y);
      }
      // prefetch next step's zx for this s (zc[s] is dead now)
#pragma unroll
      for (int g = 0; g < 4; ++g)
        zn[s][g] = *(const uint2*)(zlane + znoff + (size_t)(g * 16 + wid * 2 + s) * 512);

#pragma unroll
      for (int kc = 0; kc < 8; ++kc){
        const s16x8 hv = *(const s16x8*)(hread + c16 * 512 + ((kc * 64 + r16 * 16) ^ ((c16 & 7) << 4)));
        acc[0] = __builtin_amdgcn_mfma_f32_16x16x32_bf16(wf[0 + s][kc], hv, acc[0], 0, 0, 0);
        acc[1] = __builtin_amdgcn_mfma_f32_16x16x32_bf16(wf[2 + s][kc], hv, acc[1], 0, 0, 0);
        acc[2] = __builtin_amdgcn_mfma_f32_16x16x32_bf16(wf[4 + s][kc], hv, acc[2], 0, 0, 0);
        const s16x8 av = *(const s16x8*)(smem + ((wid * 2 + s) << 13) + (kc << 10) + lane * 16);
        acc[3] = __builtin_amdgcn_mfma_f32_16x16x32_bf16(av, hv, acc[3], 0, 0, 0);
      }
      const int q0 = (wid * 2 + s) * 16 + r16 * 4;
      float ho[4];
#pragma unroll
      for (int i = 0; i < 4; ++i){
        const float fg = sigf(__cosf(acc[0][i]));
        const float ig = sigf(__cosf(acc[1][i]));
        const float gg = tanhf_(__cosf(acc[2][i]));
        const float og = sigf(__cosf(acc[3][i]));
        const float cn = fg * cst[s][i] + ig * gg;
        cst[s][i] = cn;
        ho[i] = og * tanhf_(cn);
      }
      *(float4*)(out + ((size_t)t * B_ + b) * H_ + q0) = make_float4(ho[0], ho[1], ho[2], ho[3]);
      hpack[s][0] = pk2(ho[0], ho[1]);
      hpack[s][1] = pk2(ho[2], ho[3]);
      // h for next step -> other parity buffer (R2 swizzled layout)
      *(uint2*)(hwrite + c16 * 512 + ((q0 * 2) ^ ((c16 & 7) << 4))) =
          make_uint2(hpack[s][0], hpack[s][1]);
      if (t == T_ - 1){
        float* hl = out + (size_t)T_ * B_ * H_;
        *(float4*)(hl + (size_t)b * H_ + q0) = make_float4(ho[0], ho[1], ho[2], ho[3]);
        float* cl = hl + (size_t)B_ * H_;
        *(float4*)(cl + (size_t)b * H_ + q0) = make_float4(cst[s][0], cst[s][1], cst[s][2], cst[s][3]);
      }
    }
    __syncthreads();   // one barrier per step: h writes visible, all reads done
#pragma unroll
    for (int s = 0; s < 2; ++s)
#pragma unroll
      for (int g = 0; g < 4; ++g)
        zc[s][g] = zn[s][g];
  }

  if (t0 + TC < T_){
#pragma unroll
    for (int s = 0; s < 2; ++s){
      const int q0 = (wid * 2 + s) * 16 + r16 * 4;
      *(uint2*)((char*)sh + (size_t)b * 512 + q0 * 2) = make_uint2(hpack[s][0], hpack[s][1]);
      *(float4*)(sc + (size_t)b * 256 + q0) = make_float4(cst[s][0], cst[s][1], cst[s][2], cst[s][3]);
    }
  }
}

extern "C" void kernel_launch(void* const* d_in, const int* in_sizes, int n_in,
                              void* d_out, int out_size, void* d_ws, size_t ws_size,
                              hipStream_t stream)
{
  const float* x    = (const float*)d_in[0];   // [T,B,D] f32
  const float* W    = (const float*)d_in[1];   // [4,H,D+H] f32
  const float* bias = (const float*)d_in[2];   // [4,H] f32
  float* out = (float*)d_out;                  // outputs | h_last | c_last (f32)

  char* ws = (char*)d_ws;
  u16*   Wxb = (u16*)(ws);                     // 512 KB frag layout
  u16*   Whb = (u16*)(ws + 524288);            // 512 KB frag layout
  u16*   sh  = (u16*)(ws + 1048576);           // 128 KB h state (chunk spill)
  float* sc  = (float*)(ws + 1179648);         // 256 KB c state
  u16*   xb  = (u16*)(ws + 1441792);           // 64 MB x frag layout
  const unsigned long long zx_off = 1441792ull + (unsigned long long)T_ * B_ * D_ * 2ull;
  u16*   zxf = (u16*)(ws + zx_off);            // zx fragment buffer

  (void)hipFuncSetAttribute((const void*)k_phase1, hipFuncAttributeMaxDynamicSharedMemorySize, 131072);
  (void)hipFuncSetAttribute((const void*)k_phase2, hipFuncAttributeMaxDynamicSharedMemorySize, 147456);

  int TC = 8;
  const int cands[7] = {512, 256, 128, 64, 32, 16, 8};
  for (int i = 0; i < 7; ++i){
    if (zx_off + (unsigned long long)cands[i] * 524288ull <= (unsigned long long)ws_size){
      TC = cands[i];
      break;
    }
  }

  k_cast<<<256, 256, 0, stream>>>(W, Wxb, Whb);
  k_cast_x<<<16384, 256, 0, stream>>>(x, xb);
  for (int t0 = 0; t0 < T_; t0 += TC){
    k_phase1<<<dim3((TC + 7) / 8, 8, 1), 512, 131072, stream>>>(Wxb, xb, bias, zxf, t0);
    k_phase2<<<dim3(16, 1, 1), 512, 147456, stream>>>(Whb, zxf, out, sh, sc, t0, TC);
  }
}